// Round 1
// baseline (436.744 us; speedup 1.0000x reference)
//
#include <hip/hip_runtime.h>
#include <hip/hip_fp16.h>
#include <math.h>

#define VOL (96*96*96)
#define KCLS 5

// ws layout (doubles): [0..9] sumL per (b,k) vol, [10..19] sumIL, [20..24] numer[k], [25..29] denom[k]

// ---------------- kernel A: per-(b,k) sums of L and I*L ----------------
__global__ __launch_bounds__(256) void k_sums(const float* __restrict__ I,
                                              const float* __restrict__ L,
                                              double* __restrict__ ws) {
  const int vol = blockIdx.y;
  const int b = vol / KCLS;
  const float4* __restrict__ I4 = (const float4*)(I + b * VOL);
  const float4* __restrict__ L4 = (const float4*)(L + vol * VOL);
  const int idx = blockIdx.x * 256 + threadIdx.x;
  float sL = 0.f, sIL = 0.f;
#pragma unroll
  for (int j = 0; j < 4; ++j) {
    float4 iv = I4[idx + j * 55296];
    float4 lv = L4[idx + j * 55296];
    sL += (lv.x + lv.y) + (lv.z + lv.w);
    sIL += iv.x * lv.x + iv.y * lv.y + iv.z * lv.z + iv.w * lv.w;
  }
#pragma unroll
  for (int off = 32; off; off >>= 1) {
    sL += __shfl_down(sL, off);
    sIL += __shfl_down(sIL, off);
  }
  __shared__ double red[8];
  const int wid = threadIdx.x >> 6;
  if ((threadIdx.x & 63) == 0) { red[wid] = (double)sL; red[4 + wid] = (double)sIL; }
  __syncthreads();
  if (threadIdx.x == 0) {
    atomicAdd(&ws[vol], red[0] + red[1] + red[2] + red[3]);
    atomicAdd(&ws[10 + vol], red[4] + red[5] + red[6] + red[7]);
  }
}

// ---------------- kernel B: fused weights + 9^3 conv + reduce ----------------
// Tile: 16x16x16 outputs per block (256 threads). Staged halo: 24x24x24, fp16 in LDS,
// x-stride padded to 28. Each thread: 2 z-outputs x 8 x-outputs x 2 fields in registers.

#define ACC9(KW, AD, AN)                                   \
  _Pragma("unroll") for (int dx = 0; dx < 9; ++dx) {       \
    const float kwv_ = KW[dx];                             \
    _Pragma("unroll") for (int r = 0; r < 8; ++r) {        \
      AD[r] = fmaf(kwv_, rw[dx + r], AD[r]);               \
      AN[r] = fmaf(kwv_, rl[dx + r], AN[r]);               \
    }                                                      \
  }

#define LOADKW(KW, S2)                                     \
  _Pragma("unroll") for (int dx = 0; dx < 9; ++dx) {       \
    const int dd_ = dx - 4;                                \
    KW[dx] = KT[(S2) + dd_ * dd_];                         \
  }

#define LOADROWS(P)                                                        \
  {                                                                        \
    const int base_ = (((zb + (P)) * 24 + sy) * 28) + xg * 8;              \
    _Pragma("unroll") for (int j = 0; j < 4; ++j) {                        \
      float2 wr_ = *(const float2*)(Wh + base_ + 4 * j);                   \
      float2 lr_ = *(const float2*)(LWh + base_ + 4 * j);                  \
      __half2 w01_ = *(const __half2*)&wr_.x;                              \
      __half2 w23_ = *(const __half2*)&wr_.y;                              \
      __half2 l01_ = *(const __half2*)&lr_.x;                              \
      __half2 l23_ = *(const __half2*)&lr_.y;                              \
      float2 a_ = __half22float2(w01_);                                    \
      float2 b_ = __half22float2(w23_);                                    \
      float2 c_ = __half22float2(l01_);                                    \
      float2 e_ = __half22float2(l23_);                                    \
      rw[4 * j + 0] = a_.x; rw[4 * j + 1] = a_.y;                          \
      rw[4 * j + 2] = b_.x; rw[4 * j + 3] = b_.y;                          \
      rl[4 * j + 0] = c_.x; rl[4 * j + 1] = c_.y;                          \
      rl[4 * j + 2] = e_.x; rl[4 * j + 3] = e_.y;                          \
    }                                                                      \
  }

__global__ __launch_bounds__(256, 2) void k_conv(const float* __restrict__ I,
                                                 const float* __restrict__ L,
                                                 double* __restrict__ ws) {
  __shared__ __half Wh[24 * 24 * 28];
  __shared__ __half LWh[24 * 24 * 28];
  __shared__ float KT[49];
  __shared__ double red[8];

  const int t = threadIdx.x;
  const int vz = blockIdx.z;
  const int vol = vz / 6;
  const int zt = vz - vol * 6;
  const int kcl = vol % KCLS;
  const int b = vol / KCLS;
  const int x0 = blockIdx.x * 16, y0 = blockIdx.y * 16, z0 = zt * 16;

  const float* __restrict__ Ib = I + b * VOL;
  const float* __restrict__ Lb = L + vol * VOL;

  const double sLd = ws[vol];
  const double sILd = ws[10 + vol];
  const float mean = (float)(sILd / (sLd + 1e-5 * (double)VOL));

  if (t < 49) KT[t] = __expf(-(float)(t * t) * 0.02f);

  // ---- stage: compute w = exp(-(I-mean)^4) and L*w into fp16 LDS (zero halo) ----
  for (int i = 0; i < 54; ++i) {
    const int s = t + i * 256;          // 0..13823 over 24x24x24
    const int sx = s % 24;
    const int r2 = s / 24;
    const int sy_ = r2 % 24;
    const int sz_ = r2 / 24;
    const int gx = x0 - 4 + sx, gy = y0 - 4 + sy_, gz = z0 - 4 + sz_;
    const bool inb = ((unsigned)gx < 96u) && ((unsigned)gy < 96u) && ((unsigned)gz < 96u);
    float iv = 0.f, lv = 0.f;
    if (inb) {
      const int g = (gz * 96 + gy) * 96 + gx;
      iv = Ib[g];
      lv = Lb[g];
    }
    const float d = iv - mean;
    const float d2 = d * d;
    const float w = inb ? __expf(-d2 * d2) : 0.f;
    const int a = (sz_ * 24 + sy_) * 28 + sx;
    Wh[a] = __float2half(w);
    LWh[a] = __float2half(lv * w);
  }
  __syncthreads();

  // ---- conv main loop ----
  const int xg = t & 1;
  const int y = (t >> 1) & 15;
  const int zb = (t >> 5) << 1;   // z-pair base: 0,2,...,14

  float aN0[8], aD0[8], aN1[8], aD1[8];
#pragma unroll
  for (int r = 0; r < 8; ++r) { aN0[r] = 0.f; aD0[r] = 0.f; aN1[r] = 0.f; aD1[r] = 0.f; }

  float rw[16], rl[16], kw0[9], kw1[9];

#pragma unroll 1
  for (int dy = 0; dy < 9; ++dy) {
    const int sy = y + dy;
    const int dy2 = (dy - 4) * (dy - 4);
    // plane p = 0: feeds zo0 only (dz index 0)
    LOADROWS(0)
    LOADKW(kw0, 16 + dy2)
    ACC9(kw0, aD0, aN0)
#pragma unroll 1
    for (int pp = 1; pp <= 7; pp += 2) {
      LOADROWS(pp)
      const int pk = pp - 4;
      LOADKW(kw1, pk * pk + dy2)
      ACC9(kw1, aD0, aN0)   // zo0, dz=pp
      ACC9(kw0, aD1, aN1)   // zo1, dz=pp-1 (prev plane's weights)
      LOADROWS(pp + 1)
      const int qk = pp - 3;
      LOADKW(kw0, qk * qk + dy2)
      ACC9(kw0, aD0, aN0)   // zo0, dz=pp+1
      ACC9(kw1, aD1, aN1)   // zo1, dz=pp
    }
    // plane p = 9: feeds zo1 only (dz index 8); kw0 holds s2=16+dy2 from plane 8
    LOADROWS(9)
    ACC9(kw0, aD1, aN1)
  }

  // ---- epilogue: multiply by labels, reduce, atomic accumulate ----
  float pN = 0.f, pD = 0.f;
  {
    const int g0 = ((z0 + zb) * 96 + (y0 + y)) * 96 + x0 + xg * 8;
    float4 l0 = *(const float4*)(Lb + g0);
    float4 l1 = *(const float4*)(Lb + g0 + 4);
    pN += aN0[0] * l0.x + aN0[1] * l0.y + aN0[2] * l0.z + aN0[3] * l0.w
        + aN0[4] * l1.x + aN0[5] * l1.y + aN0[6] * l1.z + aN0[7] * l1.w;
    pD += aD0[0] * l0.x + aD0[1] * l0.y + aD0[2] * l0.z + aD0[3] * l0.w
        + aD0[4] * l1.x + aD0[5] * l1.y + aD0[6] * l1.z + aD0[7] * l1.w;
    const int g1 = g0 + 96 * 96;
    float4 m0 = *(const float4*)(Lb + g1);
    float4 m1 = *(const float4*)(Lb + g1 + 4);
    pN += aN1[0] * m0.x + aN1[1] * m0.y + aN1[2] * m0.z + aN1[3] * m0.w
        + aN1[4] * m1.x + aN1[5] * m1.y + aN1[6] * m1.z + aN1[7] * m1.w;
    pD += aD1[0] * m0.x + aD1[1] * m0.y + aD1[2] * m0.z + aD1[3] * m0.w
        + aD1[4] * m1.x + aD1[5] * m1.y + aD1[6] * m1.z + aD1[7] * m1.w;
  }
#pragma unroll
  for (int off = 32; off; off >>= 1) {
    pN += __shfl_down(pN, off);
    pD += __shfl_down(pD, off);
  }
  const int wid = t >> 6;
  if ((t & 63) == 0) { red[wid] = (double)pN; red[4 + wid] = (double)pD; }
  __syncthreads();
  if (t == 0) {
    atomicAdd(&ws[20 + kcl], red[0] + red[1] + red[2] + red[3]);
    atomicAdd(&ws[25 + kcl], red[4] + red[5] + red[6] + red[7]);
  }
}

// ---------------- kernel C: finalize ----------------
__global__ void k_final(const double* __restrict__ ws, float* __restrict__ out) {
  if (threadIdx.x == 0 && blockIdx.x == 0) {
    double loss = 0.0;
    for (int k = 0; k < KCLS; ++k) {
      loss += fabs(ws[20 + k] / (ws[25 + k] + 1e-6));
    }
    out[0] = (float)(5.0 - loss);
  }
}

extern "C" void kernel_launch(void* const* d_in, const int* in_sizes, int n_in,
                              void* d_out, int out_size, void* d_ws, size_t ws_size,
                              hipStream_t stream) {
  (void)in_sizes; (void)n_in; (void)out_size; (void)ws_size;
  const float* I = (const float*)d_in[0];
  const float* L = (const float*)d_in[1];
  double* ws = (double*)d_ws;
  float* out = (float*)d_out;

  hipMemsetAsync(d_ws, 0, 32 * sizeof(double), stream);
  k_sums<<<dim3(216, 10, 1), 256, 0, stream>>>(I, L, ws);
  k_conv<<<dim3(6, 6, 60), 256, 0, stream>>>(I, L, ws);
  k_final<<<1, 64, 0, stream>>>(ws, out);
}

// Round 2
// 395.853 us; speedup vs baseline: 1.1033x; 1.1033x over previous
//
#include <hip/hip_runtime.h>
#include <hip/hip_fp16.h>
#include <math.h>

#define VOL (96*96*96)
#define KCLS 5

typedef _Float16 half2_t __attribute__((ext_vector_type(2)));

__device__ __forceinline__ float fdot2(half2_t a, half2_t b, float c) {
  return __builtin_amdgcn_fdot2(a, b, c, false);
}
__device__ __forceinline__ half2_t bc_h2(float f) {
  return __builtin_bit_cast(half2_t, f);
}

// ws layout (doubles): [0..9] sumL per (b,k) vol, [10..19] sumIL, [20..24] numer[k], [25..29] denom[k]

// ---------------- kernel A: per-(b,k) sums of L and I*L ----------------
__global__ __launch_bounds__(256) void k_sums(const float* __restrict__ I,
                                              const float* __restrict__ L,
                                              double* __restrict__ ws) {
  const int vol = blockIdx.y;
  const int b = vol / KCLS;
  const float4* __restrict__ I4 = (const float4*)(I + b * VOL);
  const float4* __restrict__ L4 = (const float4*)(L + vol * VOL);
  const int idx = blockIdx.x * 256 + threadIdx.x;
  float sL = 0.f, sIL = 0.f;
#pragma unroll
  for (int j = 0; j < 4; ++j) {
    float4 iv = I4[idx + j * 55296];
    float4 lv = L4[idx + j * 55296];
    sL += (lv.x + lv.y) + (lv.z + lv.w);
    sIL += iv.x * lv.x + iv.y * lv.y + iv.z * lv.z + iv.w * lv.w;
  }
#pragma unroll
  for (int off = 32; off; off >>= 1) {
    sL += __shfl_down(sL, off);
    sIL += __shfl_down(sIL, off);
  }
  __shared__ double red[8];
  const int wid = threadIdx.x >> 6;
  if ((threadIdx.x & 63) == 0) { red[wid] = (double)sL; red[4 + wid] = (double)sIL; }
  __syncthreads();
  if (threadIdx.x == 0) {
    atomicAdd(&ws[vol], red[0] + red[1] + red[2] + red[3]);
    atomicAdd(&ws[10 + vol], red[4] + red[5] + red[6] + red[7]);
  }
}

// ---------------- kernel B: fused weights + 9^3 conv + reduce ----------------
// Tile: 16x16x16 outputs per block (256 threads). Staged halo: 24x24x24, fp16 in LDS,
// x-stride padded to 28. Each thread: 2 z-outputs x 8 x-outputs x 2 fields.
// Inner loop: v_dot2_f32_f16 (2 fp16 MACs, f32 accum) on packed half2 rows — no cvts.
// Tap pairs precomputed per s2=(dy-4)^2+(dz-4)^2 in LDS: even-output pairs (k0,k1)..(k8,0),
// odd-output pairs (0,k0),(k1,k2)..(k7,k8).

#define ACC(KE, KO, AD, AN)                                  \
  _Pragma("unroll") for (int m = 0; m < 5; ++m) {            \
    _Pragma("unroll") for (int s = 0; s < 4; ++s) {          \
      AD[2*s]   = fdot2(KE[m], rwp[s+m], AD[2*s]);           \
      AD[2*s+1] = fdot2(KO[m], rwp[s+m], AD[2*s+1]);         \
      AN[2*s]   = fdot2(KE[m], rlp[s+m], AN[2*s]);           \
      AN[2*s+1] = fdot2(KO[m], rlp[s+m], AN[2*s+1]);         \
    }                                                        \
  }

#define LOADKW(KE, KO, S2)                                   \
  {                                                          \
    const float* kp_ = KWT + (S2) * 12;                      \
    float4 e_ = *(const float4*)(kp_);                       \
    float4 o_ = *(const float4*)(kp_ + 4);                   \
    float2 x_ = *(const float2*)(kp_ + 8);                   \
    KE[0] = bc_h2(e_.x); KE[1] = bc_h2(e_.y);                \
    KE[2] = bc_h2(e_.z); KE[3] = bc_h2(e_.w);                \
    KO[0] = bc_h2(o_.x); KO[1] = bc_h2(o_.y);                \
    KO[2] = bc_h2(o_.z); KO[3] = bc_h2(o_.w);                \
    KE[4] = bc_h2(x_.x); KO[4] = bc_h2(x_.y);                \
  }

#define LOADROWS(P)                                                        \
  {                                                                        \
    const int base_ = (((zb + (P)) * 24 + sy) * 28) + xg * 8;              \
    float2 w0_ = *(const float2*)(Wh + base_);                             \
    float2 w1_ = *(const float2*)(Wh + base_ + 4);                         \
    float2 w2_ = *(const float2*)(Wh + base_ + 8);                         \
    float2 w3_ = *(const float2*)(Wh + base_ + 12);                        \
    float2 l0_ = *(const float2*)(LWh + base_);                            \
    float2 l1_ = *(const float2*)(LWh + base_ + 4);                        \
    float2 l2_ = *(const float2*)(LWh + base_ + 8);                        \
    float2 l3_ = *(const float2*)(LWh + base_ + 12);                       \
    rwp[0] = bc_h2(w0_.x); rwp[1] = bc_h2(w0_.y);                          \
    rwp[2] = bc_h2(w1_.x); rwp[3] = bc_h2(w1_.y);                          \
    rwp[4] = bc_h2(w2_.x); rwp[5] = bc_h2(w2_.y);                          \
    rwp[6] = bc_h2(w3_.x); rwp[7] = bc_h2(w3_.y);                          \
    rlp[0] = bc_h2(l0_.x); rlp[1] = bc_h2(l0_.y);                          \
    rlp[2] = bc_h2(l1_.x); rlp[3] = bc_h2(l1_.y);                          \
    rlp[4] = bc_h2(l2_.x); rlp[5] = bc_h2(l2_.y);                          \
    rlp[6] = bc_h2(l3_.x); rlp[7] = bc_h2(l3_.y);                          \
  }

__global__ __launch_bounds__(256, 2) void k_conv(const float* __restrict__ I,
                                                 const float* __restrict__ L,
                                                 double* __restrict__ ws) {
  __shared__ __half Wh[24 * 24 * 28];
  __shared__ __half LWh[24 * 24 * 28];
  __shared__ float KWT[33 * 12];
  __shared__ double red[8];

  const int t = threadIdx.x;
  const int vz = blockIdx.z;
  const int vol = vz / 6;
  const int zt = vz - vol * 6;
  const int kcl = vol % KCLS;
  const int b = vol / KCLS;
  const int x0 = blockIdx.x * 16, y0 = blockIdx.y * 16, z0 = zt * 16;

  const float* __restrict__ Ib = I + b * VOL;
  const float* __restrict__ Lb = L + vol * VOL;

  const double sLd = ws[vol];
  const double sILd = ws[10 + vol];
  const float mean = (float)(sILd / (sLd + 1e-5 * (double)VOL));

  // ---- precompute fp16 tap-pair table: s2 in [0,32] ----
  if (t < 33) {
    float kk[10];
#pragma unroll
    for (int d = 0; d < 9; ++d) {
      const int dd = d - 4;
      const float q = (float)(t + dd * dd);
      kk[d] = __expf(-0.02f * q * q);
    }
    kk[9] = 0.f;
#pragma unroll
    for (int m = 0; m < 4; ++m) {
      half2_t e; e.x = (_Float16)kk[2 * m]; e.y = (_Float16)kk[2 * m + 1];
      KWT[t * 12 + m] = __builtin_bit_cast(float, e);
      half2_t o; o.x = (m == 0) ? (_Float16)0.f : (_Float16)kk[2 * m - 1];
      o.y = (_Float16)kk[2 * m];
      KWT[t * 12 + 4 + m] = __builtin_bit_cast(float, o);
    }
    half2_t e4; e4.x = (_Float16)kk[8]; e4.y = (_Float16)0.f;
    KWT[t * 12 + 8] = __builtin_bit_cast(float, e4);
    half2_t o4; o4.x = (_Float16)kk[7]; o4.y = (_Float16)kk[8];
    KWT[t * 12 + 9] = __builtin_bit_cast(float, o4);
  }

  // ---- stage: w = exp(-(I-mean)^4) and L*w into fp16 LDS (zero halo) ----
  for (int i = 0; i < 54; ++i) {
    const int s = t + i * 256;          // 0..13823 over 24x24x24
    const int sx = s % 24;
    const int r2 = s / 24;
    const int sy_ = r2 % 24;
    const int sz_ = r2 / 24;
    const int gx = x0 - 4 + sx, gy = y0 - 4 + sy_, gz = z0 - 4 + sz_;
    const bool inb = ((unsigned)gx < 96u) && ((unsigned)gy < 96u) && ((unsigned)gz < 96u);
    float iv = 0.f, lv = 0.f;
    if (inb) {
      const int g = (gz * 96 + gy) * 96 + gx;
      iv = Ib[g];
      lv = Lb[g];
    }
    const float d = iv - mean;
    const float d2 = d * d;
    const float w = inb ? __expf(-d2 * d2) : 0.f;
    const int a = (sz_ * 24 + sy_) * 28 + sx;
    Wh[a] = __float2half(w);
    LWh[a] = __float2half(lv * w);
  }
  __syncthreads();

  // ---- conv main loop ----
  const int xg = t & 1;
  const int y = (t >> 1) & 15;
  const int zb = (t >> 5) << 1;   // z-pair base: 0,2,...,14

  float aN0[8], aD0[8], aN1[8], aD1[8];
#pragma unroll
  for (int r = 0; r < 8; ++r) { aN0[r] = 0.f; aD0[r] = 0.f; aN1[r] = 0.f; aD1[r] = 0.f; }

  half2_t rwp[8], rlp[8];
  half2_t kwE0[5], kwO0[5], kwE1[5], kwO1[5];

#pragma unroll 1
  for (int dy = 0; dy < 9; ++dy) {
    const int sy = y + dy;
    const int dy2 = (dy - 4) * (dy - 4);
    // plane p = 0: feeds zo0 only (dz index 0, s2 = 16 + dy2)
    LOADROWS(0)
    LOADKW(kwE0, kwO0, 16 + dy2)
    ACC(kwE0, kwO0, aD0, aN0)
#pragma unroll 1
    for (int pp = 1; pp <= 7; pp += 2) {
      LOADROWS(pp)
      const int pk = pp - 4;
      LOADKW(kwE1, kwO1, pk * pk + dy2)
      ACC(kwE1, kwO1, aD0, aN0)   // zo0, dz=pp
      ACC(kwE0, kwO0, aD1, aN1)   // zo1, dz=pp-1 (prev plane's taps)
      LOADROWS(pp + 1)
      const int qk = pp - 3;
      LOADKW(kwE0, kwO0, qk * qk + dy2)
      ACC(kwE0, kwO0, aD0, aN0)   // zo0, dz=pp+1
      ACC(kwE1, kwO1, aD1, aN1)   // zo1, dz=pp
    }
    // plane p = 9: feeds zo1 only (dz index 8); kwE0/kwO0 hold s2=16+dy2 from plane 8
    LOADROWS(9)
    ACC(kwE0, kwO0, aD1, aN1)
  }

  // ---- epilogue: multiply by labels, reduce, atomic accumulate ----
  float pN = 0.f, pD = 0.f;
  {
    const int g0 = ((z0 + zb) * 96 + (y0 + y)) * 96 + x0 + xg * 8;
    float4 l0 = *(const float4*)(Lb + g0);
    float4 l1 = *(const float4*)(Lb + g0 + 4);
    pN += aN0[0] * l0.x + aN0[1] * l0.y + aN0[2] * l0.z + aN0[3] * l0.w
        + aN0[4] * l1.x + aN0[5] * l1.y + aN0[6] * l1.z + aN0[7] * l1.w;
    pD += aD0[0] * l0.x + aD0[1] * l0.y + aD0[2] * l0.z + aD0[3] * l0.w
        + aD0[4] * l1.x + aD0[5] * l1.y + aD0[6] * l1.z + aD0[7] * l1.w;
    const int g1 = g0 + 96 * 96;
    float4 m0 = *(const float4*)(Lb + g1);
    float4 m1 = *(const float4*)(Lb + g1 + 4);
    pN += aN1[0] * m0.x + aN1[1] * m0.y + aN1[2] * m0.z + aN1[3] * m0.w
        + aN1[4] * m1.x + aN1[5] * m1.y + aN1[6] * m1.z + aN1[7] * m1.w;
    pD += aD1[0] * m0.x + aD1[1] * m0.y + aD1[2] * m0.z + aD1[3] * m0.w
        + aD1[4] * m1.x + aD1[5] * m1.y + aD1[6] * m1.z + aD1[7] * m1.w;
  }
#pragma unroll
  for (int off = 32; off; off >>= 1) {
    pN += __shfl_down(pN, off);
    pD += __shfl_down(pD, off);
  }
  const int wid = t >> 6;
  if ((t & 63) == 0) { red[wid] = (double)pN; red[4 + wid] = (double)pD; }
  __syncthreads();
  if (t == 0) {
    atomicAdd(&ws[20 + kcl], red[0] + red[1] + red[2] + red[3]);
    atomicAdd(&ws[25 + kcl], red[4] + red[5] + red[6] + red[7]);
  }
}

// ---------------- kernel C: finalize ----------------
__global__ void k_final(const double* __restrict__ ws, float* __restrict__ out) {
  if (threadIdx.x == 0 && blockIdx.x == 0) {
    double loss = 0.0;
    for (int k = 0; k < KCLS; ++k) {
      loss += fabs(ws[20 + k] / (ws[25 + k] + 1e-6));
    }
    out[0] = (float)(5.0 - loss);
  }
}

extern "C" void kernel_launch(void* const* d_in, const int* in_sizes, int n_in,
                              void* d_out, int out_size, void* d_ws, size_t ws_size,
                              hipStream_t stream) {
  (void)in_sizes; (void)n_in; (void)out_size; (void)ws_size;
  const float* I = (const float*)d_in[0];
  const float* L = (const float*)d_in[1];
  double* ws = (double*)d_ws;
  float* out = (float*)d_out;

  hipMemsetAsync(d_ws, 0, 32 * sizeof(double), stream);
  k_sums<<<dim3(216, 10, 1), 256, 0, stream>>>(I, L, ws);
  k_conv<<<dim3(6, 6, 60), 256, 0, stream>>>(I, L, ws);
  k_final<<<1, 64, 0, stream>>>(ws, out);
}

// Round 3
// 196.418 us; speedup vs baseline: 2.2235x; 2.0154x over previous
//
#include <hip/hip_runtime.h>
#include <math.h>

#define VOL (96*96*96)
#define KCLS 5
#define CZ 12             // z-outputs per block
#define PSTR 56           // staged plane x-stride (shorts); 112B rows -> conflict-free b128
#define PROWS 40          // staged plane y-rows (32 + 8 halo)
#define PSZ (PROWS*PSTR)  // 2240 shorts per plane buffer
#define ZOFF (33*256)     // zero-slot offset in A-table (shorts)

typedef __attribute__((ext_vector_type(8))) short bf16x8;
typedef __attribute__((ext_vector_type(4))) float f32x4;
typedef __attribute__((ext_vector_type(4))) unsigned short us4;

__device__ __forceinline__ unsigned short f2bf(float f) {
  unsigned u = __builtin_bit_cast(unsigned, f);
  u += 0x7fffu + ((u >> 16) & 1u);
  return (unsigned short)(u >> 16);
}

// ws layout (doubles): [0..9] sumL per (b,k), [10..19] sumIL, [20..24] numer[k], [25..29] denom[k]

// ---------------- kernel A: per-(b,k) sums of L and I*L ----------------
__global__ __launch_bounds__(256) void k_sums(const float* __restrict__ I,
                                              const float* __restrict__ L,
                                              double* __restrict__ ws) {
  const int vol = blockIdx.y;
  const int b = vol / KCLS;
  const float4* __restrict__ I4 = (const float4*)(I + b * VOL);
  const float4* __restrict__ L4 = (const float4*)(L + vol * VOL);
  const int idx = blockIdx.x * 256 + threadIdx.x;
  float sL = 0.f, sIL = 0.f;
#pragma unroll
  for (int j = 0; j < 4; ++j) {
    float4 iv = I4[idx + j * 55296];
    float4 lv = L4[idx + j * 55296];
    sL += (lv.x + lv.y) + (lv.z + lv.w);
    sIL += iv.x * lv.x + iv.y * lv.y + iv.z * lv.z + iv.w * lv.w;
  }
#pragma unroll
  for (int off = 32; off; off >>= 1) {
    sL += __shfl_down(sL, off);
    sIL += __shfl_down(sIL, off);
  }
  __shared__ double red[8];
  const int wid = threadIdx.x >> 6;
  if ((threadIdx.x & 63) == 0) { red[wid] = (double)sL; red[4 + wid] = (double)sIL; }
  __syncthreads();
  if (threadIdx.x == 0) {
    atomicAdd(&ws[vol], red[0] + red[1] + red[2] + red[3]);
    atomicAdd(&ws[10 + vol], red[4] + red[5] + red[6] + red[7]);
  }
}

// ---------------- kernel B: MFMA banded-matmul 3D conv ----------------
// Per wave: 16x outputs (m) x 16y outputs (n). Block = 4 waves = 32x * 32y tile, CZ z-outputs.
// x-conv as banded matmul: D[m][n] += A^(s2)[m][k] * P[k][n], A[m][k]=tap(k-m), zero for k>=24.
// z handled by sliding ring of 9 accumulators per field; planes staged double-buffered in bf16.
__global__ __launch_bounds__(256) void k_conv(const float* __restrict__ I,
                                              const float* __restrict__ L,
                                              double* __restrict__ ws) {
  __shared__ __attribute__((aligned(16))) short Atab[ZOFF + 8];
  __shared__ __attribute__((aligned(16))) short Wp[2][PSZ];
  __shared__ __attribute__((aligned(16))) short LWp[2][PSZ];
  __shared__ double red[8];

  const int t = threadIdx.x;
  const int vol = blockIdx.z;
  const int kcl = vol % KCLS;
  const int b = vol / KCLS;
  const int x0 = (blockIdx.x % 3) * 32;
  const int y0 = (blockIdx.x / 3) * 32;
  const int z0 = blockIdx.y * CZ;

  const float* __restrict__ Ib = I + b * VOL;
  const float* __restrict__ Lb = L + vol * VOL;

  const double sLd = ws[vol];
  const float mean = (float)(ws[10 + vol] / (sLd + 1e-5 * (double)VOL));

  // ---- build A-table: 33 s2-values x 32 shifts x 8 bf16 (+ 8-short zero slot) ----
  for (int i = 0; i < 33; ++i) {
    const int idx = i * 256 + t;          // 0..8447
    const int s2 = idx >> 8;
    const int rem = idx & 255;
    const int R = rem >> 3, j = rem & 7;
    const int dx = R - 15 + j;            // band index into v[0..8]
    float val = 0.f;
    if (dx >= 0 && dx <= 8) {
      const float q = (float)(s2 + (dx - 4) * (dx - 4));
      val = __expf(-0.02f * q * q);
    }
    Atab[idx] = (short)f2bf(val);
  }
  if (t < 8) Atab[ZOFF + t] = 0;

  // ---- lane constants ----
  const int lane = t & 63;
  const int w = t >> 6;
  const int wx = w & 1, wy = w >> 1;
  const int nn = lane & 15, qq = lane >> 4;
  const int aBase = (qq < 3) ? ((8 * qq - nn + 15) * 8) : ZOFF;
  const int aMask = (qq < 3) ? -1 : 0;
  const int bBase = (16 * wy + nn) * PSTR + 16 * wx + 8 * qq;

  f32x4 accW[9], accL[9];
  const f32x4 zer = {0.f, 0.f, 0.f, 0.f};
#pragma unroll
  for (int i = 0; i < 9; ++i) { accW[i] = zer; accL[i] = zer; }
  float pN = 0.f, pD = 0.f;

  // ---- staging helpers (quad = 4 consecutive x in one halo row) ----
  auto loadQuad = [&](int zp, int qi, float4& iv, float4& lv, bool& ok) {
    const int row = qi / 12;
    const int xq = (qi - row * 12) * 4;
    const int gy = y0 - 4 + row, gx = x0 - 4 + xq;
    ok = ((unsigned)zp < 96u) && ((unsigned)gy < 96u) && ((unsigned)gx <= 92u);
    if (ok) {
      const int off = (zp * 96 + gy) * 96 + gx;
      iv = *(const float4*)(Ib + off);
      lv = *(const float4*)(Lb + off);
    } else {
      iv = make_float4(0.f, 0.f, 0.f, 0.f);
      lv = make_float4(0.f, 0.f, 0.f, 0.f);
    }
  };
  auto storeQuad = [&](int buf, int qi, const float4& iv, const float4& lv, bool ok) {
    const int row = qi / 12;
    const int xq = (qi - row * 12) * 4;
    float d, w0, w1, w2, w3;
    d = iv.x - mean; d = d * d; w0 = ok ? __expf(-d * d) : 0.f;
    d = iv.y - mean; d = d * d; w1 = ok ? __expf(-d * d) : 0.f;
    d = iv.z - mean; d = d * d; w2 = ok ? __expf(-d * d) : 0.f;
    d = iv.w - mean; d = d * d; w3 = ok ? __expf(-d * d) : 0.f;
    us4 wv = { f2bf(w0), f2bf(w1), f2bf(w2), f2bf(w3) };
    us4 ov = { f2bf(lv.x * w0), f2bf(lv.y * w1), f2bf(lv.z * w2), f2bf(lv.w * w3) };
    *(us4*)(&Wp[buf][row * PSTR + xq]) = wv;
    *(us4*)(&LWp[buf][row * PSTR + xq]) = ov;
  };

  // ---- compute one staged plane zp against the 9-deep accumulator ring ----
  auto computePlane = [&](int buf, int zp) {
    const short* __restrict__ Wb = Wp[buf];
    const short* __restrict__ Lwb = LWp[buf];
    int iLo = z0 - (zp - 4); if (iLo < 0) iLo = 0;
    int iHi = (z0 + CZ - 1) - (zp - 4); if (iHi > 8) iHi = 8;
#pragma unroll 1
    for (int dy = 0; dy < 9; ++dy) {
      const int dy2 = (dy - 4) * (dy - 4);
      bf16x8 af[5];
#pragma unroll
      for (int da = 0; da < 5; ++da) {
        const int s2 = dy2 + da * da;
        af[da] = *(const bf16x8*)(Atab + aBase + ((s2 << 8) & aMask));
      }
      const int boff = bBase + dy * PSTR;
      const bf16x8 bw = *(const bf16x8*)(Wb + boff);
      const bf16x8 bl = *(const bf16x8*)(Lwb + boff);
#pragma unroll
      for (int i = 0; i < 9; ++i) {
        if (i >= iLo && i <= iHi) {
          const int da = (i < 4) ? (4 - i) : (i - 4);
          accW[i] = __builtin_amdgcn_mfma_f32_16x16x32_bf16(af[da], bw, accW[i], 0, 0, 0);
          accL[i] = __builtin_amdgcn_mfma_f32_16x16x32_bf16(af[da], bl, accL[i], 0, 0, 0);
        }
      }
    }
  };

  // ---- retire output plane zo (= acc slot 0), then slide the ring ----
  auto retire = [&](int zo) {
    if (zo >= z0 && zo < z0 + CZ) {
      const int gy = y0 + 16 * wy + nn;
      const int gx = x0 + 16 * wx + 4 * qq;
      const float4 lab = *(const float4*)(Lb + (zo * 96 + gy) * 96 + gx);
      pN += accL[0].x * lab.x + accL[0].y * lab.y + accL[0].z * lab.z + accL[0].w * lab.w;
      pD += accW[0].x * lab.x + accW[0].y * lab.y + accW[0].z * lab.z + accW[0].w * lab.w;
    }
#pragma unroll
    for (int i = 0; i < 8; ++i) { accW[i] = accW[i + 1]; accL[i] = accL[i + 1]; }
    accW[8] = zer; accL[8] = zer;
  };

  // ---- main z-pipeline ----
  const int zp0 = z0 - 4;
  const int zend = z0 + CZ + 4;   // exclusive
  {
    float4 i0, l0, i1, l1; bool o0, o1;
    loadQuad(zp0, t, i0, l0, o0);
    storeQuad(0, t, i0, l0, o0);
    if (t < 224) { loadQuad(zp0, 256 + t, i1, l1, o1); storeQuad(0, 256 + t, i1, l1, o1); }
  }
  __syncthreads();

  for (int zp = zp0; zp < zend; ++zp) {
    const int cur = (zp - zp0) & 1;
    const bool more = (zp + 1 < zend);
    float4 i0, l0, i1, l1; bool o0 = false, o1 = false;
    if (more) {
      loadQuad(zp + 1, t, i0, l0, o0);
      if (t < 224) loadQuad(zp + 1, 256 + t, i1, l1, o1);
    }
    computePlane(cur, zp);
    retire(zp - 4);
    if (more) {
      storeQuad(cur ^ 1, t, i0, l0, o0);
      if (t < 224) storeQuad(cur ^ 1, 256 + t, i1, l1, o1);
    }
    __syncthreads();
  }

  // ---- reduce & accumulate ----
#pragma unroll
  for (int off = 32; off; off >>= 1) {
    pN += __shfl_down(pN, off);
    pD += __shfl_down(pD, off);
  }
  if (lane == 0) { red[w] = (double)pN; red[4 + w] = (double)pD; }
  __syncthreads();
  if (t == 0) {
    atomicAdd(&ws[20 + kcl], red[0] + red[1] + red[2] + red[3]);
    atomicAdd(&ws[25 + kcl], red[4] + red[5] + red[6] + red[7]);
  }
}

// ---------------- kernel C: finalize ----------------
__global__ void k_final(const double* __restrict__ ws, float* __restrict__ out) {
  if (threadIdx.x == 0 && blockIdx.x == 0) {
    double loss = 0.0;
    for (int k = 0; k < KCLS; ++k) {
      loss += fabs(ws[20 + k] / (ws[25 + k] + 1e-6));
    }
    out[0] = (float)(5.0 - loss);
  }
}

extern "C" void kernel_launch(void* const* d_in, const int* in_sizes, int n_in,
                              void* d_out, int out_size, void* d_ws, size_t ws_size,
                              hipStream_t stream) {
  (void)in_sizes; (void)n_in; (void)out_size; (void)ws_size;
  const float* I = (const float*)d_in[0];
  const float* L = (const float*)d_in[1];
  double* ws = (double*)d_ws;
  float* out = (float*)d_out;

  hipMemsetAsync(d_ws, 0, 32 * sizeof(double), stream);
  k_sums<<<dim3(216, 10, 1), 256, 0, stream>>>(I, L, ws);
  k_conv<<<dim3(9, 8, 10), 256, 0, stream>>>(I, L, ws);
  k_final<<<1, 64, 0, stream>>>(ws, out);
}

// Round 4
// 192.132 us; speedup vs baseline: 2.2731x; 1.0223x over previous
//
#include <hip/hip_runtime.h>
#include <math.h>

#define VOL (96*96*96)
#define KCLS 5
#define CZ 12             // z-outputs per block
#define PSTR 64           // swizzled plane x-stride (shorts); 16B-chunk XOR swizzle
#define PROWS 40          // staged plane y-rows (32 + 8 halo)
#define PSZ (PROWS*PSTR)  // 2560 shorts per plane buffer
#define NS2 15            // distinct s2 = dy^2+dz^2 values

typedef __attribute__((ext_vector_type(8))) short bf16x8;
typedef __attribute__((ext_vector_type(4))) float f32x4;
typedef __attribute__((ext_vector_type(4))) unsigned short us4;

// distinct s2 values and s2 -> fragment-register index map (compile-time folded)
constexpr int S2VALS[NS2] = {0,1,2,4,5,8,9,10,13,16,17,18,20,25,32};
constexpr int MAP33[33] = {0,1,2,-1,3,4,-1,-1,5,6,7,-1,-1,8,-1,-1,
                           9,10,11,-1,12,-1,-1,-1,-1,13,-1,-1,-1,-1,-1,-1,14};

__device__ __forceinline__ unsigned short f2bf(float f) {
  unsigned u = __builtin_bit_cast(unsigned, f);
  u += 0x7fffu + ((u >> 16) & 1u);
  return (unsigned short)(u >> 16);
}

// ws layout (doubles): [0..9] sumL per (b,k), [10..19] sumIL, [20..24] numer[k], [25..29] denom[k]

// ---------------- kernel A: per-(b,k) sums of L and I*L (I read once) ----------------
__global__ __launch_bounds__(256) void k_sums(const float* __restrict__ I,
                                              const float* __restrict__ L,
                                              double* __restrict__ ws) {
  const int b = blockIdx.y;
  const int base = blockIdx.x * 2048 + threadIdx.x;   // float4 units; 108*2048 = VOL/4
  const float4* __restrict__ I4 = (const float4*)(I + b * VOL);
  float4 iv[8];
#pragma unroll
  for (int j = 0; j < 8; ++j) iv[j] = I4[base + j * 256];
  float sL[KCLS], sIL[KCLS];
#pragma unroll
  for (int k = 0; k < KCLS; ++k) { sL[k] = 0.f; sIL[k] = 0.f; }
#pragma unroll 1
  for (int k = 0; k < KCLS; ++k) {
    const float4* __restrict__ L4 = (const float4*)(L + (b * KCLS + k) * VOL);
#pragma unroll
    for (int j = 0; j < 8; ++j) {
      float4 lv = L4[base + j * 256];
      sL[k] += (lv.x + lv.y) + (lv.z + lv.w);
      sIL[k] += iv[j].x * lv.x + iv[j].y * lv.y + iv[j].z * lv.z + iv[j].w * lv.w;
    }
  }
#pragma unroll
  for (int k = 0; k < KCLS; ++k) {
#pragma unroll
    for (int off = 32; off; off >>= 1) {
      sL[k] += __shfl_down(sL[k], off);
      sIL[k] += __shfl_down(sIL[k], off);
    }
  }
  __shared__ double red[4][2 * KCLS];
  const int wid = threadIdx.x >> 6;
  if ((threadIdx.x & 63) == 0) {
#pragma unroll
    for (int k = 0; k < KCLS; ++k) {
      red[wid][k] = (double)sL[k];
      red[wid][KCLS + k] = (double)sIL[k];
    }
  }
  __syncthreads();
  if (threadIdx.x < 2 * KCLS) {
    double v = red[0][threadIdx.x] + red[1][threadIdx.x] + red[2][threadIdx.x] + red[3][threadIdx.x];
    const int k = threadIdx.x % KCLS;
    const int which = threadIdx.x / KCLS;
    atomicAdd(&ws[(which ? 10 : 0) + b * KCLS + k], v);
  }
}

// ---------------- kernel B: MFMA banded-matmul 3D conv ----------------
// A-fragments (15 distinct s2) pre-expanded to per-lane layout, held in registers.
// Plane LDS uses 16B-chunk XOR swizzle (c ^ (row&7)) -> conflict-free b128 reads/writes.
__global__ __launch_bounds__(256, 2) void k_conv(const float* __restrict__ I,
                                                 const float* __restrict__ L,
                                                 double* __restrict__ ws) {
  __shared__ __attribute__((aligned(16))) short AtabF[NS2 * 64 * 8];  // 15360 B
  __shared__ __attribute__((aligned(16))) short Wp[2][PSZ];
  __shared__ __attribute__((aligned(16))) short LWp[2][PSZ];
  __shared__ double red[8];

  const int t = threadIdx.x;
  const int vol = blockIdx.z;
  const int kcl = vol % KCLS;
  const int b = vol / KCLS;
  const int x0 = (blockIdx.x % 3) * 32;
  const int y0 = (blockIdx.x / 3) * 32;
  const int z0 = blockIdx.y * CZ;

  const float* __restrict__ Ib = I + b * VOL;
  const float* __restrict__ Lb = L + vol * VOL;

  const double sLd = ws[vol];
  const float mean = (float)(ws[10 + vol] / (sLd + 1e-5 * (double)VOL));

  // ---- build per-lane A-fragment table: 15 s2 x 64 lanes x 8 bf16 ----
#pragma unroll
  for (int s2i = 0; s2i < NS2; ++s2i) {
    const float s2c = (float)S2VALS[s2i];
#pragma unroll
    for (int h = 0; h < 2; ++h) {
      const int sub = t + h * 256;          // 0..511
      const int lane_ = sub >> 3;
      const int j = sub & 7;
      const int dx = ((lane_ >> 4) << 3) + j - (lane_ & 15);  // k - m
      float val = 0.f;
      if (dx >= 0 && dx <= 8) {
        const float q = s2c + (float)((dx - 4) * (dx - 4));
        val = __expf(-0.02f * q * q);
      }
      AtabF[s2i * 512 + sub] = (short)f2bf(val);
    }
  }

  // ---- lane constants ----
  const int lane = t & 63;
  const int w = t >> 6;
  const int wx = w & 1, wy = w >> 1;
  const int nn = lane & 15, qq = lane >> 4;

  f32x4 accW[9], accL[9];
  const f32x4 zer = {0.f, 0.f, 0.f, 0.f};
#pragma unroll
  for (int i = 0; i < 9; ++i) { accW[i] = zer; accL[i] = zer; }
  float pN = 0.f, pD = 0.f;

  // ---- staging helpers (quad = 4 consecutive x in one halo row; swizzled store) ----
  auto loadQuad = [&](int zp, int qi, float4& iv, float4& lv, bool& ok) {
    const int row = qi / 12;
    const int xq = (qi - row * 12) * 4;
    const int gy = y0 - 4 + row, gx = x0 - 4 + xq;
    ok = ((unsigned)zp < 96u) && ((unsigned)gy < 96u) && ((unsigned)gx <= 92u);
    if (ok) {
      const int off = (zp * 96 + gy) * 96 + gx;
      iv = *(const float4*)(Ib + off);
      lv = *(const float4*)(Lb + off);
    } else {
      iv = make_float4(0.f, 0.f, 0.f, 0.f);
      lv = make_float4(0.f, 0.f, 0.f, 0.f);
    }
  };
  auto storeQuad = [&](int buf, int qi, const float4& iv, const float4& lv, bool ok) {
    const int row = qi / 12;
    const int q = qi - row * 12;
    const int c = q >> 1, o = (q & 1) << 2;
    const int a = row * PSTR + (((c ^ (row & 7)) << 3) + o);
    float d, w0, w1, w2, w3;
    d = iv.x - mean; d = d * d; w0 = ok ? __expf(-d * d) : 0.f;
    d = iv.y - mean; d = d * d; w1 = ok ? __expf(-d * d) : 0.f;
    d = iv.z - mean; d = d * d; w2 = ok ? __expf(-d * d) : 0.f;
    d = iv.w - mean; d = d * d; w3 = ok ? __expf(-d * d) : 0.f;
    us4 wv = { f2bf(w0), f2bf(w1), f2bf(w2), f2bf(w3) };
    us4 ov = { f2bf(lv.x * w0), f2bf(lv.y * w1), f2bf(lv.z * w2), f2bf(lv.w * w3) };
    *(us4*)(&Wp[buf][a]) = wv;
    *(us4*)(&LWp[buf][a]) = ov;
  };

  // ---- stage plane 0, then load A-fragments into registers ----
  {
    float4 i0, l0, i1, l1; bool o0, o1;
    loadQuad(z0 - 4, t, i0, l0, o0);
    storeQuad(0, t, i0, l0, o0);
    if (t < 224) { loadQuad(z0 - 4, 256 + t, i1, l1, o1); storeQuad(0, 256 + t, i1, l1, o1); }
  }
  __syncthreads();

  bf16x8 afr[NS2];
#pragma unroll
  for (int r = 0; r < NS2; ++r)
    afr[r] = *(const bf16x8*)(AtabF + (r * 64 + lane) * 8);

  // ---- plane-compute bodies ----
  auto computeFull = [&](int buf) {
    const short* __restrict__ Wb = Wp[buf];
    const short* __restrict__ Lwb = LWp[buf];
#pragma unroll
    for (int dy = 0; dy < 9; ++dy) {
      const int dy2c = (dy - 4) * (dy - 4);
      const int yrow = 16 * wy + nn + dy;
      const int boff = yrow * PSTR + ((((2 * wx + qq) ^ (yrow & 7))) << 3);
      const bf16x8 bw = *(const bf16x8*)(Wb + boff);
      const bf16x8 bl = *(const bf16x8*)(Lwb + boff);
#pragma unroll
      for (int i = 0; i < 9; ++i) {
        const int da = (i < 4) ? (4 - i) : (i - 4);
        const int ri = MAP33[dy2c + da * da];
        accW[i] = __builtin_amdgcn_mfma_f32_16x16x32_bf16(afr[ri], bw, accW[i], 0, 0, 0);
        accL[i] = __builtin_amdgcn_mfma_f32_16x16x32_bf16(afr[ri], bl, accL[i], 0, 0, 0);
      }
    }
  };
  auto computeEdge = [&](int buf, int iLo, int iHi) {
    const short* __restrict__ Wb = Wp[buf];
    const short* __restrict__ Lwb = LWp[buf];
#pragma unroll
    for (int dy = 0; dy < 9; ++dy) {
      const int dy2c = (dy - 4) * (dy - 4);
      const int yrow = 16 * wy + nn + dy;
      const int boff = yrow * PSTR + ((((2 * wx + qq) ^ (yrow & 7))) << 3);
      const bf16x8 bw = *(const bf16x8*)(Wb + boff);
      const bf16x8 bl = *(const bf16x8*)(Lwb + boff);
#pragma unroll
      for (int i = 0; i < 9; ++i) {
        if (i >= iLo && i <= iHi) {
          const int da = (i < 4) ? (4 - i) : (i - 4);
          const int ri = MAP33[dy2c + da * da];
          accW[i] = __builtin_amdgcn_mfma_f32_16x16x32_bf16(afr[ri], bw, accW[i], 0, 0, 0);
          accL[i] = __builtin_amdgcn_mfma_f32_16x16x32_bf16(afr[ri], bl, accL[i], 0, 0, 0);
        }
      }
    }
  };

  // ---- retire output plane zo (= acc slot 0), then slide the ring ----
  auto retire = [&](int zo) {
    if (zo >= z0 && zo < z0 + CZ) {
      const int gy = y0 + 16 * wy + nn;
      const int gx = x0 + 16 * wx + 4 * qq;
      const float4 lab = *(const float4*)(Lb + (zo * 96 + gy) * 96 + gx);
      pN += accL[0].x * lab.x + accL[0].y * lab.y + accL[0].z * lab.z + accL[0].w * lab.w;
      pD += accW[0].x * lab.x + accW[0].y * lab.y + accW[0].z * lab.z + accW[0].w * lab.w;
    }
#pragma unroll
    for (int i = 0; i < 8; ++i) { accW[i] = accW[i + 1]; accL[i] = accL[i + 1]; }
    accW[8] = zer; accL[8] = zer;
  };

  // ---- main z-pipeline ----
  const int zp0 = z0 - 4;
  const int zend = z0 + CZ + 4;   // exclusive
  for (int zp = zp0; zp < zend; ++zp) {
    const int cur = (zp - zp0) & 1;
    const bool more = (zp + 1 < zend);
    float4 i0, l0, i1, l1; bool o0 = false, o1 = false;
    if (more) {
      loadQuad(zp + 1, t, i0, l0, o0);
      if (t < 224) loadQuad(zp + 1, 256 + t, i1, l1, o1);
    }
    int iLo = z0 - (zp - 4); if (iLo < 0) iLo = 0;
    int iHi = (z0 + CZ - 1) - (zp - 4); if (iHi > 8) iHi = 8;
    if (iLo == 0 && iHi == 8) computeFull(cur);
    else computeEdge(cur, iLo, iHi);
    retire(zp - 4);
    if (more) {
      storeQuad(cur ^ 1, t, i0, l0, o0);
      if (t < 224) storeQuad(cur ^ 1, 256 + t, i1, l1, o1);
    }
    __syncthreads();
  }

  // ---- reduce & accumulate ----
#pragma unroll
  for (int off = 32; off; off >>= 1) {
    pN += __shfl_down(pN, off);
    pD += __shfl_down(pD, off);
  }
  if (lane == 0) { red[w] = (double)pN; red[4 + w] = (double)pD; }
  __syncthreads();
  if (t == 0) {
    atomicAdd(&ws[20 + kcl], red[0] + red[1] + red[2] + red[3]);
    atomicAdd(&ws[25 + kcl], red[4] + red[5] + red[6] + red[7]);
  }
}

// ---------------- kernel C: finalize ----------------
__global__ void k_final(const double* __restrict__ ws, float* __restrict__ out) {
  if (threadIdx.x == 0 && blockIdx.x == 0) {
    double loss = 0.0;
    for (int k = 0; k < KCLS; ++k) {
      loss += fabs(ws[20 + k] / (ws[25 + k] + 1e-6));
    }
    out[0] = (float)(5.0 - loss);
  }
}

extern "C" void kernel_launch(void* const* d_in, const int* in_sizes, int n_in,
                              void* d_out, int out_size, void* d_ws, size_t ws_size,
                              hipStream_t stream) {
  (void)in_sizes; (void)n_in; (void)out_size; (void)ws_size;
  const float* I = (const float*)d_in[0];
  const float* L = (const float*)d_in[1];
  double* ws = (double*)d_ws;
  float* out = (float*)d_out;

  hipMemsetAsync(d_ws, 0, 32 * sizeof(double), stream);
  k_sums<<<dim3(108, 2, 1), 256, 0, stream>>>(I, L, ws);
  k_conv<<<dim3(9, 8, 10), 256, 0, stream>>>(I, L, ws);
  k_final<<<1, 64, 0, stream>>>(ws, out);
}